// Round 11
// baseline (193.773 us; speedup 1.0000x reference)
//
#include <hip/hip_runtime.h>
#include <hip/hip_fp16.h>
#include <math.h>

// TriangleAttentionStartingNode: B=1, N=256, C=128, H=4, AC=32, fp32 in/out.
// R6:  precision-lite pipeline (bf16 q/k/v/P, fp16 g, hi/lo out-GEMM).
// R10: WIN(204->194) - full fusion; mega 122.8us.
// R11: FAILED(270) - hipLaunchCooperativeKernel = ~110us harness overhead.
// R12: WIN - 16-wave mega (4 waves/SIMD): 122.8->93.5us.
// R13: small WIN - LN hoisted to pre (aLN bf16), mega 89us.
// R15: WIN - zero-movement P/epilogue via v_mfma_f32_16x16x16bf16_1k: 76.4us.
// R16: NEUTRAL - 4-chain ILP widen changed nothing (VGPR 64, same 76us):
//      chain-ILP not the limiter. Accounting: pre + dispatch gap ~110us vs
//      mega 76 -> the pre dispatch IS the remaining cost.
// R17: IN-KERNEL GRID BARRIER. mega grid = 256 blocks @138KB LDS -> HW can
//      host only 1 block/CU and there are 256 CUs => all blocks co-resident
//      BY CONSTRUCTION => atomic-counter barrier is deadlock-free without
//      cooperative launch. Phase A (R12's 16-wave LN, 4 lanes/row) + nb
//      slice (block m owns nb[h,i=m,:]) -> nbP; release-add; projections
//      run while others finish; spin-acquire (cross-XCD inv) only before
//      attention. pre dispatch + aLN (29MB traffic) deleted; prep kernel
//      (tiny, 40 blocks) also zeroes the counter each graph iteration.

#define NRES 256
#define CCH  128
#define NROWS (NRES * NRES)          // 65536
#define FACTOR 0.17677669529663687f  // 1/sqrt(32)
#define LOG2E  1.44269504088896341f

typedef __attribute__((ext_vector_type(8))) __bf16 bf16x8;
typedef __attribute__((ext_vector_type(4))) float f32x4;
typedef __attribute__((ext_vector_type(4))) short s16x4;

__device__ __forceinline__ f32x4 mfma16(bf16x8 a, bf16x8 b, f32x4 c) {
    return __builtin_amdgcn_mfma_f32_16x16x32_bf16(a, b, c, 0, 0, 0);
}
// K=16 variant: A/B = 4 bf16 (2 VGPRs). A: m=l15, k=quad*4+e.
// B: n=l15, k=quad*4+e. D: lane holds D[m=quad*4+r][n=l15].
__device__ __forceinline__ f32x4 mfma16x16(s16x4 a, s16x4 b, f32x4 c) {
    return __builtin_amdgcn_mfma_f32_16x16x16bf16_1k(a, b, c, 0, 0, 0);
}

union PK4 { __bf16 b[4]; uint2 u2; s16x4 s4; };

__device__ __forceinline__ void hilo(float x, __bf16& h, __bf16& l) {
    h = (__bf16)x;
    l = (__bf16)(x - (float)h);
}

// ---- dispatch 1 (tiny): weight prep + barrier-counter zero ---------------
__global__ __launch_bounds__(256) void prep_kernel(
    const float* __restrict__ wq, const float* __restrict__ wk,
    const float* __restrict__ wv, const float* __restrict__ wg,
    const float* __restrict__ wo,
    __bf16* __restrict__ wph, __bf16* __restrict__ wo16h,
    __bf16* __restrict__ wo16l, unsigned* __restrict__ cnt)
{
    const int t = threadIdx.x;
    if (blockIdx.x == 0 && t == 0) *cnt = 0;   // visible to mega via dispatch boundary
    const int gid = blockIdx.x * 256 + t;      // 0..10239
    const int wid = gid >> 11;
    const int rem = gid & 2047;
    const int lane = rem & 63;
    const int l15 = lane & 15, quad = lane >> 4;
    if (wid < 4) {
        // q/k/v/g: x32 B-frag layout (hi only); q scaled by F*log2e
        const int nstrip = rem >> 8;
        const int kf = (rem >> 6) & 3;
        const float* W = (wid == 0) ? wq : (wid == 1) ? wk :
                         (wid == 2) ? wv : wg;
        const float scale = (wid == 0) ? FACTOR * LOG2E : 1.0f;
        bf16x8 hb;
        #pragma unroll
        for (int e = 0; e < 8; ++e) {
            int k = kf * 32 + quad * 8 + e;
            int n = nstrip * 16 + l15;
            hb[e] = (__bf16)(W[k * CCH + n] * scale);
        }
        *(bf16x8*)&wph[(size_t)gid * 8] = hb;
    } else {
        // wo: x16 B-frag layout, hi/lo split.
        const int nstrip = rem >> 8;
        const int kcp = (rem >> 6) & 3;
        #pragma unroll
        for (int sub = 0; sub < 2; ++sub) {
            const int kc = kcp * 2 + sub;
            PK4 hh, ll;
            #pragma unroll
            for (int e = 0; e < 4; ++e) {
                int k = kc * 16 + quad * 4 + e;
                int n = nstrip * 16 + l15;
                __bf16 h, l; hilo(wo[k * CCH + n], h, l);
                hh.b[e] = h; ll.b[e] = l;
            }
            const int fo = ((nstrip * 8 + kc) * 64 + lane) * 4;
            *(uint2*)&wo16h[fo] = hh.u2;
            *(uint2*)&wo16l[fo] = ll.u2;
        }
    }
}

// ---------------- projection helper: 16 rows x 128 out-ch -----------------
__device__ __forceinline__ void proj16(const bf16x8* A0,
    const __bf16* __restrict__ Bh, int lane, f32x4* acc)
{
    #pragma unroll
    for (int n = 0; n < 8; ++n) acc[n] = (f32x4){0.f, 0.f, 0.f, 0.f};
    #pragma unroll
    for (int kf = 0; kf < 4; ++kf)
        #pragma unroll
        for (int n = 0; n < 8; ++n) {
            bf16x8 bh = *(const bf16x8*)&Bh[(size_t)((n * 4 + kf) * 64 + lane) * 8];
            acc[n] = mfma16(A0[kf], bh, acc[n]);
        }
}

// ---------------- mega kernel (fused, grid-barrier) -----------------------
// One block per pair-row m, 1024 threads (16 waves, 4/SIMD), 1 block/CU
// FORCED by 138KB LDS => 256 blocks on 256 CUs, all co-resident.
// LDS: [0)      K / wave planes: 16 x [16][136] bf16 = 69632 B (K[256][136])
//      [69632)  V^T [128][264] bf16                  = 67584 B
//      [137216) biasrow [256] f32                    =  1024 B  tot 138240
__global__ __launch_bounds__(1024) void mega_kernel(
    const float* __restrict__ act, const float* __restrict__ ln_g,
    const float* __restrict__ ln_b, const float* __restrict__ w2d,
    const __bf16* __restrict__ wph, const __bf16* __restrict__ wo16h,
    const __bf16* __restrict__ wo16l, const float* __restrict__ bg,
    const float* __restrict__ mask, float* __restrict__ nbP,
    const float* __restrict__ bo, unsigned* __restrict__ cnt,
    float* __restrict__ out)
{
    __shared__ __align__(16) char smem[138240];
    const int t = threadIdx.x, w = t >> 6, lane = t & 63;
    const int l15 = lane & 15, quad = lane >> 4;
    const int m = blockIdx.x;
    __bf16* const Kl = (__bf16*)smem;                        // [256][136]
    __bf16* const aH = (__bf16*)(smem + w * 4352);           // plane w [16][136]
    __bf16* const VT = (__bf16*)(smem + 69632);              // [128][264]
    float*  const biasrow = (float*)(smem + 137216);         // [256]

    // mask bias with log2e and the -4 exp-offset folded in
    if (t < 256)
        biasrow[t] = fmaf(1.442695e9f, mask[m * NRES + t] - 1.0f, -4.0f * LOG2E);

    // ---- Phase A: LN of this wave's 16 rows -> own plane (4 lanes/row),
    //      plus this block's nb slice nb[h, i=m, j] -> nbP ----
    {
        const int row = lane >> 2, gq = lane & 3;   // 16 rows, 32 ch/lane
        const int grow = m * NRES + w * 16 + row;
        const float* __restrict__ xp = act + (size_t)grow * CCH + gq * 32;
        float4 x4[8];
        #pragma unroll
        for (int c = 0; c < 8; ++c) x4[c] = *(const float4*)(xp + c * 4);
        float s = 0.f, sq = 0.f;
        #pragma unroll
        for (int c = 0; c < 8; ++c) {
            s  += (x4[c].x + x4[c].y) + (x4[c].z + x4[c].w);
            sq += x4[c].x * x4[c].x + x4[c].y * x4[c].y +
                  x4[c].z * x4[c].z + x4[c].w * x4[c].w;
        }
        #pragma unroll
        for (int o = 1; o <= 2; o <<= 1) {
            s  += __shfl_xor(s, o, 64);
            sq += __shfl_xor(sq, o, 64);
        }
        float mu  = s * (1.0f / CCH);
        float var = fmaf(sq, 1.0f / CCH, -mu * mu);
        float rs  = rsqrtf(var + 1e-5f);
        float nb[4] = {0.f, 0.f, 0.f, 0.f};
        const float4* __restrict__ w2d4 = (const float4*)w2d;
        #pragma unroll
        for (int c2 = 0; c2 < 4; ++c2) {
            bf16x8 pk;
            #pragma unroll
            for (int cc = 0; cc < 2; ++cc) {
                const int c = c2 * 2 + cc;
                float4 g4 = *(const float4*)&ln_g[gq * 32 + c * 4];
                float4 b4 = *(const float4*)&ln_b[gq * 32 + c * 4];
                float* xv = (float*)&x4[c];
                float* gv = (float*)&g4;
                float* bv = (float*)&b4;
                #pragma unroll
                for (int e = 0; e < 4; ++e) {
                    float av = fmaf((xv[e] - mu) * rs, gv[e], bv[e]);
                    pk[cc * 4 + e] = (__bf16)av;
                    float4 wv = w2d4[gq * 32 + c * 4 + e];
                    nb[0] = fmaf(av, wv.x, nb[0]);
                    nb[1] = fmaf(av, wv.y, nb[1]);
                    nb[2] = fmaf(av, wv.z, nb[2]);
                    nb[3] = fmaf(av, wv.w, nb[3]);
                }
            }
            *(bf16x8*)&aH[row * 136 + gq * 32 + c2 * 8] = pk;
        }
        #pragma unroll
        for (int o = 1; o <= 2; o <<= 1)
            #pragma unroll
            for (int hh = 0; hh < 4; ++hh)
                nb[hh] += __shfl_xor(nb[hh], o, 64);
        if (gq == 0) {
            const int j = w * 16 + row;           // i == m
            #pragma unroll
            for (int hh = 0; hh < 4; ++hh) {
                int f = (hh << 14) + ((m >> 4) << 10) + ((j >> 4) << 6) +
                        (((j >> 2) & 3) << 4) + (m & 15);
                nbP[f * 4 + (j & 3)] = nb[hh] * LOG2E;
            }
        }
    }
    __syncthreads();   // all nbP stores issued; aH planes ready
    if (t == 0)
        __hip_atomic_fetch_add(cnt, 1u, __ATOMIC_RELEASE,
                               __HIP_MEMORY_SCOPE_AGENT);

    // ---- A-frags from own plane (projections overlap other blocks' PhaseA)
    bf16x8 A0[4];
    #pragma unroll
    for (int kf = 0; kf < 4; ++kf)
        A0[kf] = *(const bf16x8*)&aH[l15 * 136 + kf * 32 + quad * 8];

    f32x4 acc[8];
    bf16x8 Qh[4];             // [head] B-frag of own q rows
    uint2  greg[4][2];        // [head][c] 4 fp16 gate vals

    // ---- q: project (pre-scaled by FACTOR*log2e), restage, hoist ----
    proj16(A0, wph, lane, acc);
    {
        __bf16* const sth = aH;
        #pragma unroll
        for (int n = 0; n < 8; ++n)
            #pragma unroll
            for (int r = 0; r < 4; ++r)
                sth[(quad * 4 + r) * 136 + n * 16 + l15] = (__bf16)acc[n][r];
        #pragma unroll
        for (int h = 0; h < 4; ++h)
            Qh[h] = *(const bf16x8*)&sth[l15 * 136 + h * 32 + quad * 8];
    }

    // ---- g: project + bias + sigmoid (fp16), restage, hoist ----
    proj16(A0, wph + 3 * 16384, lane, acc);
    {
        __half* const sthH = (__half*)aH;
        #pragma unroll
        for (int n = 0; n < 8; ++n)
            #pragma unroll
            for (int r = 0; r < 4; ++r) {
                float v = acc[n][r] + bg[n * 16 + l15];
                sthH[(quad * 4 + r) * 136 + n * 16 + l15] =
                    (__half)(1.0f / (1.0f + __expf(-v)));
            }
        #pragma unroll
        for (int h = 0; h < 4; ++h)
            #pragma unroll
            for (int c = 0; c < 2; ++c)
                greg[h][c] =
                    *(const uint2*)&sthH[l15 * 136 + h * 32 + c * 16 + quad * 4];
    }

    // ---- k: project into own plane (plane row = K row w*16+..) ----
    proj16(A0, wph + 1 * 16384, lane, acc);
    #pragma unroll
    for (int n = 0; n < 8; ++n)
        #pragma unroll
        for (int r = 0; r < 4; ++r)
            aH[(quad * 4 + r) * 136 + n * 16 + l15] = (__bf16)acc[n][r];

    // ---- v: project, packed transpose-write into V^T (b64 per n) ----
    proj16(A0, wph + 2 * 16384, lane, acc);
    {
        const int jcol = w * 16 + quad * 4;
        #pragma unroll
        for (int n = 0; n < 8; ++n) {
            PK4 pv;
            #pragma unroll
            for (int r = 0; r < 4; ++r) pv.b[r] = (__bf16)acc[n][r];
            *(uint2*)&VT[(n * 16 + l15) * 264 + jcol] = pv.u2;
        }
    }

    __syncthreads();   // K/VT ready block-wide
    // ---- grid barrier: wait for all blocks' nbP (acquire = cross-XCD inv)
    if (t == 0)
        while (__hip_atomic_load(cnt, __ATOMIC_ACQUIRE,
                                 __HIP_MEMORY_SCOPE_AGENT) < 256u) {}
    __syncthreads();

    // ---- attention: 4 heads, own 16 q-rows, sweep all 256 j ----
    PK4 ovh[4][2], ovl[4][2];
    #pragma unroll
    for (int h = 0; h < 4; ++h) {
        f32x4 O[2];
        O[0] = (f32x4){0.f, 0.f, 0.f, 0.f};
        O[1] = (f32x4){0.f, 0.f, 0.f, 0.f};
        float ls = 0.f;
        const int nbbase = (h * 16384 + w * 1024 + quad * 16 + l15) * 4;
        #pragma unroll 1
        for (int jb = 0; jb < NRES; jb += 64) {
            bf16x8 Kh[4];
            #pragma unroll
            for (int u = 0; u < 4; ++u)
                Kh[u] = *(const bf16x8*)&Kl[(jb + u * 16 + l15) * 136 +
                                            h * 32 + quad * 8];
            PK4 Vf[2][4];
            #pragma unroll
            for (int c = 0; c < 2; ++c)
                #pragma unroll
                for (int u = 0; u < 4; ++u)
                    Vf[c][u].u2 = *(const uint2*)&VT[
                        (h * 32 + c * 16 + l15) * 264 + jb + u * 16 + quad * 4];
            float4 nb4[4];
            #pragma unroll
            for (int u = 0; u < 4; ++u)
                nb4[u] = *(const float4*)(nbP + nbbase +
                                          (((jb >> 4) + u) << 8));
            f32x4 S[4];
            #pragma unroll
            for (int u = 0; u < 4; ++u) {
                S[u] = (f32x4){0.f, 0.f, 0.f, 0.f};
                S[u] = mfma16(Kh[u], Qh[h], S[u]);
            }
            PK4 PJ[4];
            #pragma unroll
            for (int u = 0; u < 4; ++u) {
                float4 mb = *(const float4*)&biasrow[jb + u * 16 + quad * 4];
                float p0 = exp2f(S[u][0] + nb4[u].x + mb.x);
                float p1 = exp2f(S[u][1] + nb4[u].y + mb.y);
                float p2 = exp2f(S[u][2] + nb4[u].z + mb.z);
                float p3 = exp2f(S[u][3] + nb4[u].w + mb.w);
                ls += (p0 + p1) + (p2 + p3);
                PJ[u].b[0] = (__bf16)p0; PJ[u].b[1] = (__bf16)p1;
                PJ[u].b[2] = (__bf16)p2; PJ[u].b[3] = (__bf16)p3;
            }
            #pragma unroll
            for (int c = 0; c < 2; ++c)
                #pragma unroll
                for (int u = 0; u < 4; ++u)
                    O[c] = mfma16x16(Vf[c][u].s4, PJ[u].s4, O[c]);
        }
        ls += __shfl_xor(ls, 16, 64);
        ls += __shfl_xor(ls, 32, 64);
        float inv = 1.0f / ls;
        #pragma unroll
        for (int c = 0; c < 2; ++c) {
            const __half* gh = (const __half*)&greg[h][c];
            #pragma unroll
            for (int r = 0; r < 4; ++r) {
                float v = O[c][r] * inv * (float)gh[r];
                __bf16 hb; __bf16 lb; hilo(v, hb, lb);
                ovh[h][c].b[r] = hb; ovl[h][c].b[r] = lb;
            }
        }
    }

    // ---- out GEMM: x16 MFMAs, A-frags = ovh/ovl DIRECTLY; 3-term split ----
    {
        #pragma unroll
        for (int n = 0; n < 8; ++n) acc[n] = (f32x4){0.f, 0.f, 0.f, 0.f};
        #pragma unroll
        for (int kc = 0; kc < 8; ++kc) {
            const int h = kc >> 1, c = kc & 1;
            s16x4 Ah = ovh[h][c].s4;
            s16x4 Al = ovl[h][c].s4;
            #pragma unroll
            for (int n = 0; n < 8; ++n) {
                const int fo = ((n * 8 + kc) * 64 + lane) * 4;
                PK4 bh, bl;
                bh.u2 = *(const uint2*)&wo16h[fo];
                bl.u2 = *(const uint2*)&wo16l[fo];
                acc[n] = mfma16x16(Ah, bh.s4, acc[n]);
                acc[n] = mfma16x16(Ah, bl.s4, acc[n]);
                acc[n] = mfma16x16(Al, bh.s4, acc[n]);
            }
        }

        const size_t rbase = (size_t)m * NRES + w * 16;
        #pragma unroll
        for (int n = 0; n < 8; ++n) {
            float b = bo[n * 16 + l15];
            #pragma unroll
            for (int r = 0; r < 4; ++r)
                out[(rbase + quad * 4 + r) * CCH + n * 16 + l15] = acc[n][r] + b;
        }
    }
}

extern "C" void kernel_launch(void* const* d_in, const int* in_sizes, int n_in,
                              void* d_out, int out_size, void* d_ws, size_t ws_size,
                              hipStream_t stream)
{
    const float* act  = (const float*)d_in[0];
    const float* mask = (const float*)d_in[1];
    const float* ln_g = (const float*)d_in[2];
    const float* ln_b = (const float*)d_in[3];
    const float* wq   = (const float*)d_in[4];
    const float* wk   = (const float*)d_in[5];
    const float* wv   = (const float*)d_in[6];
    const float* w2d  = (const float*)d_in[7];
    const float* wg   = (const float*)d_in[8];
    const float* bg   = (const float*)d_in[9];
    const float* wo   = (const float*)d_in[10];
    const float* bo   = (const float*)d_in[11];
    float* out = (float*)d_out;

    float* nbP    = (float*)d_ws;                  // 4*NROWS floats = 1 MB
    __bf16* wph   = (__bf16*)(nbP + 4 * NROWS);    // 4*16384 bf16
    __bf16* wo16h = wph + 4 * 16384;               // 16384 bf16
    __bf16* wo16l = wo16h + 16384;                 // 16384 bf16
    unsigned* cnt = (unsigned*)(wo16l + 16384);    // barrier counter

    prep_kernel<<<40, 256, 0, stream>>>(
        wq, wk, wv, wg, wo, wph, wo16h, wo16l, cnt);
    mega_kernel<<<256, 1024, 0, stream>>>(
        act, ln_g, ln_b, w2d, wph, wo16h, wo16l, bg, mask, nbP, bo, cnt, out);
}

// Round 12
// 186.858 us; speedup vs baseline: 1.0370x; 1.0370x over previous
//
#include <hip/hip_runtime.h>
#include <hip/hip_fp16.h>
#include <math.h>

// TriangleAttentionStartingNode: B=1, N=256, C=128, H=4, AC=32, fp32 in/out.
// R6:  precision-lite pipeline (bf16 q/k/v/P, fp16 g, hi/lo out-GEMM).
// R10: WIN(204->194) - full fusion; mega 122.8us.
// R11: FAILED(270) - hipLaunchCooperativeKernel = ~110us harness overhead.
// R12: WIN - 16-wave mega (4 waves/SIMD): 122.8->93.5us.
// R13: small WIN - LN hoisted to pre (aLN bf16), mega 89us.
// R15: WIN - zero-movement P/epilogue via v_mfma_f32_16x16x16bf16_1k: 76.4us,
//      total 185.1 (session best).
// R16: NEUTRAL - 4-chain ILP widen (VGPR 64, same 76us).
// R17: FAILED(194) - in-kernel grid barrier: correct, but act fetch + LN +
//      straggler wait moved onto mega's critical path (+29.5us) > saved
//      dispatch (~30us). Lesson: cross-round subtraction accounting is
//      unreliable; pre is ~30us, harness fixed overhead ~70us.
// R18: revert to R15/R16 structure + fold nb+mb into the QK MFMA C-init
//      (mfma computes A*B+C): kills 16 dependent adds per head-iter and
//      shortens the S->exp2 chain; cinit adds run off the critical path.

#define NRES 256
#define CCH  128
#define NROWS (NRES * NRES)          // 65536
#define FACTOR 0.17677669529663687f  // 1/sqrt(32)
#define LOG2E  1.44269504088896341f

typedef __attribute__((ext_vector_type(8))) __bf16 bf16x8;
typedef __attribute__((ext_vector_type(4))) float f32x4;
typedef __attribute__((ext_vector_type(4))) short s16x4;

__device__ __forceinline__ f32x4 mfma16(bf16x8 a, bf16x8 b, f32x4 c) {
    return __builtin_amdgcn_mfma_f32_16x16x32_bf16(a, b, c, 0, 0, 0);
}
// K=16 variant: A/B = 4 bf16 (2 VGPRs). A: m=l15, k=quad*4+e.
// B: n=l15, k=quad*4+e. D: lane holds D[m=quad*4+r][n=l15].
__device__ __forceinline__ f32x4 mfma16x16(s16x4 a, s16x4 b, f32x4 c) {
    return __builtin_amdgcn_mfma_f32_16x16x16bf16_1k(a, b, c, 0, 0, 0);
}

union PK4 { __bf16 b[4]; uint2 u2; s16x4 s4; };

__device__ __forceinline__ void hilo(float x, __bf16& h, __bf16& l) {
    h = (__bf16)x;
    l = (__bf16)(x - (float)h);
}

// ---- dispatch 1: LN->aLN + nb (blocks 0-2047) + weight prep (2048-2087) ----
__global__ __launch_bounds__(256) void pre_kernel(
    const float* __restrict__ act, const float* __restrict__ ln_g,
    const float* __restrict__ ln_b, const float* __restrict__ w2d,
    const float* __restrict__ wq, const float* __restrict__ wk,
    const float* __restrict__ wv, const float* __restrict__ wg,
    const float* __restrict__ wo,
    __bf16* __restrict__ wph, __bf16* __restrict__ wo16h,
    __bf16* __restrict__ wo16l,
    float* __restrict__ nbP, __bf16* __restrict__ aLN)
{
    const int t = threadIdx.x;
    if (blockIdx.x >= 2048) {
        const int gid = (blockIdx.x - 2048) * 256 + t;   // 0..10239
        const int wid = gid >> 11;
        const int rem = gid & 2047;
        const int lane = rem & 63;
        const int l15 = lane & 15, quad = lane >> 4;
        if (wid < 4) {
            // q/k/v/g: x32 B-frag layout (hi only); q scaled by F*log2e
            const int nstrip = rem >> 8;
            const int kf = (rem >> 6) & 3;
            const float* W = (wid == 0) ? wq : (wid == 1) ? wk :
                             (wid == 2) ? wv : wg;
            const float scale = (wid == 0) ? FACTOR * LOG2E : 1.0f;
            bf16x8 hb;
            #pragma unroll
            for (int e = 0; e < 8; ++e) {
                int k = kf * 32 + quad * 8 + e;
                int n = nstrip * 16 + l15;
                hb[e] = (__bf16)(W[k * CCH + n] * scale);
            }
            *(bf16x8*)&wph[(size_t)gid * 8] = hb;
        } else {
            // wo: x16 B-frag layout, hi/lo split.
            // frag element e <-> k = kc*16 + quad*4 + e, n = nstrip*16+l15
            const int nstrip = rem >> 8;
            const int kcp = (rem >> 6) & 3;
            #pragma unroll
            for (int sub = 0; sub < 2; ++sub) {
                const int kc = kcp * 2 + sub;
                PK4 hh, ll;
                #pragma unroll
                for (int e = 0; e < 4; ++e) {
                    int k = kc * 16 + quad * 4 + e;
                    int n = nstrip * 16 + l15;
                    __bf16 h, l; hilo(wo[k * CCH + n], h, l);
                    hh.b[e] = h; ll.b[e] = l;
                }
                const int fo = ((nstrip * 8 + kc) * 64 + lane) * 4;
                *(uint2*)&wo16h[fo] = hh.u2;
                *(uint2*)&wo16l[fo] = ll.u2;
            }
        }
        return;
    }
    // ---- LN once: aLN (bf16) + nb (fp32 dot, log2e-folded) ----
    const int ridx = t >> 3, g = t & 7;          // 32 rows/block, 8 thr/row
    const int grow = blockIdx.x * 32 + ridx;
    const float* __restrict__ xp = act + (size_t)grow * CCH + g * 16;
    float4 x4[4];
    #pragma unroll
    for (int c = 0; c < 4; ++c) x4[c] = *(const float4*)(xp + c * 4);
    float s = 0.f, sq = 0.f;
    #pragma unroll
    for (int c = 0; c < 4; ++c) {
        s  += (x4[c].x + x4[c].y) + (x4[c].z + x4[c].w);
        sq += x4[c].x * x4[c].x + x4[c].y * x4[c].y +
              x4[c].z * x4[c].z + x4[c].w * x4[c].w;
    }
    #pragma unroll
    for (int o = 1; o <= 4; o <<= 1) {
        s  += __shfl_xor(s, o, 64);
        sq += __shfl_xor(sq, o, 64);
    }
    float mu  = s * (1.0f / CCH);
    float var = fmaf(sq, 1.0f / CCH, -mu * mu);
    float rs  = rsqrtf(var + 1e-5f);
    float av[16];
    #pragma unroll
    for (int c = 0; c < 4; ++c) {
        float4 g4 = *(const float4*)&ln_g[g * 16 + c * 4];
        float4 b4 = *(const float4*)&ln_b[g * 16 + c * 4];
        float* xv = (float*)&x4[c];
        float* gv = (float*)&g4;
        float* bv = (float*)&b4;
        #pragma unroll
        for (int e = 0; e < 4; ++e)
            av[c * 4 + e] = fmaf((xv[e] - mu) * rs, gv[e], bv[e]);
    }
    bf16x8 o1, o2;
    #pragma unroll
    for (int e = 0; e < 8; ++e) {
        o1[e] = (__bf16)av[e];
        o2[e] = (__bf16)av[8 + e];
    }
    *(bf16x8*)&aLN[(size_t)grow * CCH + g * 16] = o1;
    *(bf16x8*)&aLN[(size_t)grow * CCH + g * 16 + 8] = o2;

    float nb[4] = {0.f, 0.f, 0.f, 0.f};
    const float4* __restrict__ w2d4 = (const float4*)w2d;
    #pragma unroll
    for (int c = 0; c < 16; ++c) {
        float4 wv = w2d4[g * 16 + c];
        nb[0] = fmaf(av[c], wv.x, nb[0]);
        nb[1] = fmaf(av[c], wv.y, nb[1]);
        nb[2] = fmaf(av[c], wv.z, nb[2]);
        nb[3] = fmaf(av[c], wv.w, nb[3]);
    }
    #pragma unroll
    for (int o = 1; o <= 4; o <<= 1)
        #pragma unroll
        for (int hh = 0; hh < 4; ++hh)
            nb[hh] += __shfl_xor(nb[hh], o, 64);
    if (g == 0) {
        const int i = grow >> 8, j = grow & 255;
        #pragma unroll
        for (int hh = 0; hh < 4; ++hh) {
            size_t f = ((size_t)hh << 14) + ((size_t)(i >> 4) << 10) +
                       ((size_t)(j >> 4) << 6) + ((size_t)((j >> 2) & 3) << 4) +
                       (i & 15);
            nbP[f * 4 + (j & 3)] = nb[hh] * LOG2E;
        }
    }
}

// ---------------- projection helper: 16 rows x 128 out-ch -----------------
__device__ __forceinline__ void proj16(const bf16x8* A0,
    const __bf16* __restrict__ Bh, int lane, f32x4* acc)
{
    #pragma unroll
    for (int n = 0; n < 8; ++n) acc[n] = (f32x4){0.f, 0.f, 0.f, 0.f};
    #pragma unroll
    for (int kf = 0; kf < 4; ++kf)
        #pragma unroll
        for (int n = 0; n < 8; ++n) {
            bf16x8 bh = *(const bf16x8*)&Bh[(size_t)((n * 4 + kf) * 64 + lane) * 8];
            acc[n] = mfma16(A0[kf], bh, acc[n]);
        }
}

// ---------------- mega kernel: 16 waves, wave = 16 rows -------------------
// One block per pair-row m, 1024 threads (16 waves, 4/SIMD).
// LDS: [0)      K / wave planes: 16 x [16][136] bf16 = 69632 B (K[256][136])
//      [69632)  V^T [128][264] bf16                  = 67584 B
//      [137216) biasrow [256] f32                    =  1024 B  tot 138240
__global__ __launch_bounds__(1024) void mega_kernel(
    const __bf16* __restrict__ aLN, const __bf16* __restrict__ wph,
    const __bf16* __restrict__ wo16h, const __bf16* __restrict__ wo16l,
    const float* __restrict__ bg, const float* __restrict__ mask,
    const float* __restrict__ nbP, const float* __restrict__ bo,
    float* __restrict__ out)
{
    __shared__ __align__(16) char smem[138240];
    const int t = threadIdx.x, w = t >> 6, lane = t & 63;
    const int l15 = lane & 15, quad = lane >> 4;
    const int m = blockIdx.x;
    __bf16* const Kl = (__bf16*)smem;                        // [256][136]
    __bf16* const aH = (__bf16*)(smem + w * 4352);           // plane w [16][136]
    __bf16* const VT = (__bf16*)(smem + 69632);              // [128][264]
    float*  const biasrow = (float*)(smem + 137216);         // [256]

    // mask bias with log2e and the -4 exp-offset folded in
    if (t < 256)
        biasrow[t] = fmaf(1.442695e9f, mask[m * NRES + t] - 1.0f, -4.0f * LOG2E);

    // ---- A-frags: 4 direct global bf16x8 loads (aLN row-major) ----
    bf16x8 A0[4];
    {
        const __bf16* __restrict__ ap =
            aLN + ((size_t)m * NRES + w * 16 + l15) * CCH;
        #pragma unroll
        for (int kf = 0; kf < 4; ++kf)
            A0[kf] = *(const bf16x8*)&ap[kf * 32 + quad * 8];
    }

    f32x4 acc[8];
    bf16x8 Qh[4];             // [head] B-frag of own q rows
    uint2  greg[4][2];        // [head][c] 4 fp16 gate vals

    // ---- q: project (pre-scaled by FACTOR*log2e), restage, hoist ----
    proj16(A0, wph, lane, acc);
    {
        __bf16* const sth = aH;
        #pragma unroll
        for (int n = 0; n < 8; ++n)
            #pragma unroll
            for (int r = 0; r < 4; ++r)
                sth[(quad * 4 + r) * 136 + n * 16 + l15] = (__bf16)acc[n][r];
        #pragma unroll
        for (int h = 0; h < 4; ++h)
            Qh[h] = *(const bf16x8*)&sth[l15 * 136 + h * 32 + quad * 8];
    }

    // ---- g: project + bias + sigmoid (fp16), restage, hoist ----
    proj16(A0, wph + 3 * 16384, lane, acc);
    {
        __half* const sthH = (__half*)aH;
        #pragma unroll
        for (int n = 0; n < 8; ++n)
            #pragma unroll
            for (int r = 0; r < 4; ++r) {
                float v = acc[n][r] + bg[n * 16 + l15];
                sthH[(quad * 4 + r) * 136 + n * 16 + l15] =
                    (__half)(1.0f / (1.0f + __expf(-v)));
            }
        #pragma unroll
        for (int h = 0; h < 4; ++h)
            #pragma unroll
            for (int c = 0; c < 2; ++c)
                greg[h][c] =
                    *(const uint2*)&sthH[l15 * 136 + h * 32 + c * 16 + quad * 4];
    }

    // ---- k: project into own plane (plane row = K row w*16+..) ----
    proj16(A0, wph + 1 * 16384, lane, acc);
    #pragma unroll
    for (int n = 0; n < 8; ++n)
        #pragma unroll
        for (int r = 0; r < 4; ++r)
            aH[(quad * 4 + r) * 136 + n * 16 + l15] = (__bf16)acc[n][r];

    // ---- v: project, packed transpose-write into V^T (b64 per n) ----
    proj16(A0, wph + 2 * 16384, lane, acc);
    {
        const int jcol = w * 16 + quad * 4;
        #pragma unroll
        for (int n = 0; n < 8; ++n) {
            PK4 pv;
            #pragma unroll
            for (int r = 0; r < 4; ++r) pv.b[r] = (__bf16)acc[n][r];
            *(uint2*)&VT[(n * 16 + l15) * 264 + jcol] = pv.u2;
        }
    }

    __syncthreads();   // K/VT/biasrow ready block-wide

    // ---- attention: 4 heads, own 16 q-rows, sweep all 256 j ----
    // jb step 64 = 4 independent chains; nb+mb folded into the QK MFMA
    // C-init (mfma computes A*B+C) -> exp2 applies directly to MFMA out.
    PK4 ovh[4][2], ovl[4][2];
    #pragma unroll
    for (int h = 0; h < 4; ++h) {
        f32x4 O[2];
        O[0] = (f32x4){0.f, 0.f, 0.f, 0.f};
        O[1] = (f32x4){0.f, 0.f, 0.f, 0.f};
        float ls = 0.f;
        const int nbbase = (h * 16384 + w * 1024 + quad * 16 + l15) * 4;
        #pragma unroll 1
        for (int jb = 0; jb < NRES; jb += 64) {
            bf16x8 Kh[4];
            #pragma unroll
            for (int u = 0; u < 4; ++u)
                Kh[u] = *(const bf16x8*)&Kl[(jb + u * 16 + l15) * 136 +
                                            h * 32 + quad * 8];
            // V x16 A-frags: [c][u], m=ch(l15), k=j=quad*4+e
            PK4 Vf[2][4];
            #pragma unroll
            for (int c = 0; c < 2; ++c)
                #pragma unroll
                for (int u = 0; u < 4; ++u)
                    Vf[c][u].u2 = *(const uint2*)&VT[
                        (h * 32 + c * 16 + l15) * 264 + jb + u * 16 + quad * 4];
            // C-init = nb + mb (off the dependent path)
            f32x4 CI[4];
            #pragma unroll
            for (int u = 0; u < 4; ++u) {
                float4 nb4 = *(const float4*)(nbP + nbbase +
                                              (((jb >> 4) + u) << 8));
                float4 mb = *(const float4*)&biasrow[jb + u * 16 + quad * 4];
                CI[u] = (f32x4){nb4.x + mb.x, nb4.y + mb.y,
                                nb4.z + mb.z, nb4.w + mb.w};
            }
            // 4 independent S with folded bias
            f32x4 S[4];
            #pragma unroll
            for (int u = 0; u < 4; ++u)
                S[u] = mfma16(Kh[u], Qh[h], CI[u]);
            // 4 independent exp2+pack (directly on MFMA output)
            PK4 PJ[4];
            #pragma unroll
            for (int u = 0; u < 4; ++u) {
                float p0 = exp2f(S[u][0]);
                float p1 = exp2f(S[u][1]);
                float p2 = exp2f(S[u][2]);
                float p3 = exp2f(S[u][3]);
                ls += (p0 + p1) + (p2 + p3);
                PJ[u].b[0] = (__bf16)p0; PJ[u].b[1] = (__bf16)p1;
                PJ[u].b[2] = (__bf16)p2; PJ[u].b[3] = (__bf16)p3;
            }
            // PV: K=16 MFMAs, P straight from registers (zero movement)
            #pragma unroll
            for (int c = 0; c < 2; ++c)
                #pragma unroll
                for (int u = 0; u < 4; ++u)
                    O[c] = mfma16x16(Vf[c][u].s4, PJ[u].s4, O[c]);
        }
        ls += __shfl_xor(ls, 16, 64);
        ls += __shfl_xor(ls, 32, 64);
        float inv = 1.0f / ls;
        #pragma unroll
        for (int c = 0; c < 2; ++c) {
            const __half* gh = (const __half*)&greg[h][c];
            #pragma unroll
            for (int r = 0; r < 4; ++r) {
                float v = O[c][r] * inv * (float)gh[r];
                __bf16 hb; __bf16 lb; hilo(v, hb, lb);
                ovh[h][c].b[r] = hb; ovl[h][c].b[r] = lb;
            }
        }
    }

    // ---- out GEMM: x16 MFMAs, A-frags = ovh/ovl DIRECTLY (no LDS, no
    //      barrier, no movement); B = wo16h/wo16l; 3-term split ----
    {
        #pragma unroll
        for (int n = 0; n < 8; ++n) acc[n] = (f32x4){0.f, 0.f, 0.f, 0.f};
        #pragma unroll
        for (int kc = 0; kc < 8; ++kc) {
            const int h = kc >> 1, c = kc & 1;
            s16x4 Ah = ovh[h][c].s4;
            s16x4 Al = ovl[h][c].s4;
            #pragma unroll
            for (int n = 0; n < 8; ++n) {
                const int fo = ((n * 8 + kc) * 64 + lane) * 4;
                PK4 bh, bl;
                bh.u2 = *(const uint2*)&wo16h[fo];
                bl.u2 = *(const uint2*)&wo16l[fo];
                acc[n] = mfma16x16(Ah, bh.s4, acc[n]);
                acc[n] = mfma16x16(Ah, bl.s4, acc[n]);
                acc[n] = mfma16x16(Al, bh.s4, acc[n]);
            }
        }

        const size_t rbase = (size_t)m * NRES + w * 16;
        #pragma unroll
        for (int n = 0; n < 8; ++n) {
            float b = bo[n * 16 + l15];
            #pragma unroll
            for (int r = 0; r < 4; ++r)
                out[(rbase + quad * 4 + r) * CCH + n * 16 + l15] = acc[n][r] + b;
        }
    }
}

extern "C" void kernel_launch(void* const* d_in, const int* in_sizes, int n_in,
                              void* d_out, int out_size, void* d_ws, size_t ws_size,
                              hipStream_t stream)
{
    const float* act  = (const float*)d_in[0];
    const float* mask = (const float*)d_in[1];
    const float* ln_g = (const float*)d_in[2];
    const float* ln_b = (const float*)d_in[3];
    const float* wq   = (const float*)d_in[4];
    const float* wk   = (const float*)d_in[5];
    const float* wv   = (const float*)d_in[6];
    const float* w2d  = (const float*)d_in[7];
    const float* wg   = (const float*)d_in[8];
    const float* wo   = (const float*)d_in[10];
    const float* bg   = (const float*)d_in[9];
    const float* bo   = (const float*)d_in[11];
    float* out = (float*)d_out;

    float* nbP    = (float*)d_ws;                  // 4*NROWS floats = 1 MB
    __bf16* wph   = (__bf16*)(nbP + 4 * NROWS);    // 4*16384 bf16
    __bf16* wo16h = wph + 4 * 16384;               // 16384 bf16
    __bf16* wo16l = wo16h + 16384;                 // 16384 bf16
    __bf16* aLN   = wo16l + 16384;                 // NROWS*128 bf16 = 16 MB

    pre_kernel<<<2088, 256, 0, stream>>>(
        act, ln_g, ln_b, w2d, wq, wk, wv, wg, wo, wph, wo16h, wo16l, nbP, aLN);
    mega_kernel<<<256, 1024, 0, stream>>>(
        aLN, wph, wo16h, wo16l, bg, mask, nbP, bo, out);
}